// Round 11
// baseline (91.306 us; speedup 1.0000x reference)
//
#include <hip/hip_runtime.h>
#include <hip/hip_fp16.h>

typedef _Float16 f16;
typedef __fp16 h16x2 __attribute__((ext_vector_type(2)));
typedef _Float16 f16x8 __attribute__((ext_vector_type(8)));
typedef _Float16 f16x4v __attribute__((ext_vector_type(4)));
typedef float f32x4 __attribute__((ext_vector_type(4)));
typedef float f32x16 __attribute__((ext_vector_type(16)));
typedef unsigned int u32;
typedef u32 u32x4 __attribute__((ext_vector_type(4)));

constexpr int DM = 1024;
constexpr int HS = 64;
constexpr int NBATCH = 4;
constexpr int T = 4096;
constexpr float CEXP = 0.18033688011112042f; // 0.125 * log2(e)

#if __has_builtin(__builtin_amdgcn_exp2f)
#define EXP2(x) __builtin_amdgcn_exp2f(x)
#else
#define EXP2(x) exp2f(x)
#endif

static __device__ __forceinline__ u32 pack2_f16(float a, float b) {
  union { f16 h[2]; u32 u; } cv;
  cv.h[0] = (f16)a; cv.h[1] = (f16)b;
  return cv.u;
}

static __device__ __forceinline__ f16x8 cvt8(const f32x4& a0, const f32x4& a1) {
  union { h16x2 p[4]; f16x8 v; } cv;
  cv.p[0] = __builtin_amdgcn_cvt_pkrtz(a0[0], a0[1]);
  cv.p[1] = __builtin_amdgcn_cvt_pkrtz(a0[2], a0[3]);
  cv.p[2] = __builtin_amdgcn_cvt_pkrtz(a1[0], a1[1]);
  cv.p[3] = __builtin_amdgcn_cvt_pkrtz(a1[2], a1[3]);
  return cv.v;
}

static __device__ __forceinline__ void gload_lds16(const void* g, void* l) {
  __builtin_amdgcn_global_load_lds(
      (__attribute__((address_space(1))) void*)(g),
      (__attribute__((address_space(3))) void*)(l), 16, 0, 0);
}

// ---------------------------------------------------------------------------
// Prepass: W [1024][64] fp32 -> WTf fragment-packed fp16:
// WTf[which][frag = t*4+cb][lane = g*16+q15][e] = W[k = t*32+8g+e][col = cb*16+q15]
// ---------------------------------------------------------------------------
__global__ void wtrans_kernel(const float* __restrict__ Wq, const float* __restrict__ Wk,
                              const float* __restrict__ Wv, f16* __restrict__ WTf) {
  const int which = blockIdx.y;
  const float* __restrict__ W = (which == 0) ? Wq : ((which == 1) ? Wk : Wv);
  const int o8 = blockIdx.x * 256 + threadIdx.x;   // 0 .. 8191
  const int t = o8 >> 8;
  const int cb = (o8 >> 6) & 3;
  const int g = (o8 >> 4) & 3;
  const int q15 = o8 & 15;
  const int col = cb * 16 + q15;
  f16x8 v;
#pragma unroll
  for (int e = 0; e < 8; ++e) v[e] = (f16)W[(t * 32 + 8 * g + e) * 64 + col];
  *(f16x8*)(WTf + which * 65536 + o8 * 8) = v;
}

// ---------------------------------------------------------------------------
// Projections v9: r10's asm pipeline, now 256 blocks x 3 in-kernel phases
// (block b -> tile b of q, then k, then v; B restaged per phase). Tests
// per-CU-wall vs global-wall: 256 CUs engaged instead of 192. Depth-6
// counted vmcnt (steady 20), stores only inside phase boundaries.
// ---------------------------------------------------------------------------
__global__ __launch_bounds__(256, 1) void proj_kernel(
    const float* __restrict__ xq, const float* __restrict__ xk, const float* __restrict__ xv,
    const f16* __restrict__ WTf, f16* __restrict__ qh, f16* __restrict__ kh,
    f16* __restrict__ vhT) {
  __shared__ __align__(16) char Bs[131072];

  const int tid = threadIdx.x;
  const int lane = tid & 63, w = tid >> 6;
  const int q15 = lane & 15, g = lane >> 4;
  const int row0 = blockIdx.x * 64;

#define AISSUE(slot, G2)                                                        \
  {                                                                             \
    const size_t ab = abase + (size_t)((G2) * 256);                             \
    asm volatile("global_load_dwordx4 %0, %1, off"            : "=v"(ld[slot][0]) : "v"(ab)); \
    asm volatile("global_load_dwordx4 %0, %1, off offset:16"  : "=v"(ld[slot][1]) : "v"(ab)); \
    asm volatile("global_load_dwordx4 %0, %1, off offset:128" : "=v"(ld[slot][2]) : "v"(ab)); \
    asm volatile("global_load_dwordx4 %0, %1, off offset:144" : "=v"(ld[slot][3]) : "v"(ab)); \
  }

#define PHASE(WHICH, XP, FIRST)                                                 \
  {                                                                             \
    if (!(FIRST)) {                                                             \
      asm volatile("s_waitcnt vmcnt(0)" ::: "memory");                          \
      __builtin_amdgcn_sched_barrier(0);                                        \
      __builtin_amdgcn_s_barrier();  /* all waves done with Bs of prev phase */ \
      __builtin_amdgcn_sched_barrier(0);                                        \
    }                                                                           \
    /* stage B for this phase: 128KB, linear both sides */                      \
    {                                                                           \
      const char* wsrc = (const char*)(WTf + (size_t)(WHICH) * 65536);          \
      _Pragma("unroll") for (int j = 0; j < 32; ++j)                            \
        gload_lds16(wsrc + j * 4096 + w * 1024 + lane * 16,                     \
                    &Bs[j * 4096 + w * 1024]);                                  \
      __builtin_amdgcn_sched_barrier(0);                                        \
    }                                                                           \
    const size_t abase = (size_t)((const char*)(XP) +                           \
        (size_t)(row0 + w * 16 + q15) * 4096 + 32 * g);                         \
    f32x4 ld[8][4];                                                             \
    AISSUE(0, 0) AISSUE(1, 1) AISSUE(2, 2) AISSUE(3, 3) AISSUE(4, 4) AISSUE(5, 5) \
    asm volatile("s_waitcnt vmcnt(24)" ::: "memory");  /* B landed */           \
    __builtin_amdgcn_sched_barrier(0);                                          \
    __builtin_amdgcn_s_barrier();                                               \
    __builtin_amdgcn_sched_barrier(0);                                          \
    f32x4 acc[4];                                                               \
    _Pragma("unroll") for (int cb = 0; cb < 4; ++cb)                            \
      acc[cb] = (f32x4){0.f, 0.f, 0.f, 0.f};                                    \
    _Pragma("unroll") for (int G = 0; G < 16; ++G) {                            \
      if (G < 11)       asm volatile("s_waitcnt vmcnt(20)" ::: "memory");       \
      else if (G == 11) asm volatile("s_waitcnt vmcnt(16)" ::: "memory");       \
      else if (G == 12) asm volatile("s_waitcnt vmcnt(12)" ::: "memory");       \
      else if (G == 13) asm volatile("s_waitcnt vmcnt(8)" ::: "memory");        \
      else if (G == 14) asm volatile("s_waitcnt vmcnt(4)" ::: "memory");        \
      else              asm volatile("s_waitcnt vmcnt(0)" ::: "memory");        \
      __builtin_amdgcn_sched_barrier(0);                                        \
      if (G + 6 < 16) AISSUE((G + 6) & 7, G + 6)                                \
      const int slot = G & 7;                                                   \
      const f16x8 af0 = cvt8(ld[slot][0], ld[slot][1]);                         \
      const f16x8 af1 = cvt8(ld[slot][2], ld[slot][3]);                         \
      const char* bb = &Bs[0] + G * 8192 + lane * 16;                           \
      _Pragma("unroll") for (int cb = 0; cb < 4; ++cb) {                        \
        const f16x8 b0 = *(const f16x8*)(bb + cb * 1024);                       \
        acc[cb] = __builtin_amdgcn_mfma_f32_16x16x32_f16(af0, b0, acc[cb], 0, 0, 0); \
      }                                                                         \
      _Pragma("unroll") for (int cb = 0; cb < 4; ++cb) {                        \
        const f16x8 b1 = *(const f16x8*)(bb + 4096 + cb * 1024);                \
        acc[cb] = __builtin_amdgcn_mfma_f32_16x16x32_f16(af1, b1, acc[cb], 0, 0, 0); \
      }                                                                         \
    }                                                                           \
    /* stores (inside boundary; drained by next phase's vmcnt(0)) */            \
    if ((WHICH) < 2) {                                                          \
      f16* __restrict__ outp = ((WHICH) == 0) ? qh : kh;                        \
      const int r0 = row0 + w * 16;                                             \
      _Pragma("unroll") for (int cb = 0; cb < 4; ++cb)                          \
        _Pragma("unroll") for (int j = 0; j < 4; ++j)                           \
          outp[(size_t)(r0 + 4 * g + j) * HS + cb * 16 + q15] = (f16)acc[cb][j]; \
    } else {                                                                    \
      const int r0 = row0 + w * 16;                                             \
      const int b = r0 >> 12;                                                   \
      const int t0 = (r0 & (T - 1)) + 4 * g;                                    \
      _Pragma("unroll") for (int cb = 0; cb < 4; ++cb) {                        \
        f16x4v pv;                                                              \
        _Pragma("unroll") for (int j = 0; j < 4; ++j) pv[j] = (f16)acc[cb][j];  \
        *(f16x4v*)(vhT + (size_t)b * HS * T + (size_t)(cb * 16 + q15) * T + t0) = pv; \
      }                                                                         \
    }                                                                           \
  }

  PHASE(0, xq, true)
  PHASE(1, xk, false)
  PHASE(2, xv, false)
#undef PHASE
#undef AISSUE
}

// ---------------------------------------------------------------------------
// Causal flash attention: 32x32x16 MFMA, swapped form. (unchanged)
// ---------------------------------------------------------------------------
__global__ __launch_bounds__(512, 4) void attn_kernel(
    const f16* __restrict__ qh, const f16* __restrict__ kh,
    const f16* __restrict__ vhT, float* __restrict__ out) {
  __shared__ float sO[4][64][33];
  __shared__ float sMm[8][32];
  __shared__ float sLs[8][32];

  const int tid = threadIdx.x;
  const int lane = tid & 63, w = tid >> 6;
  const int q31 = lane & 31, hi = lane >> 5;

  const int id = blockIdx.x;
  const int b = (id & 7) >> 1;
  const int qt = 127 - 2 * (id >> 3) - (id & 1);
  const int q0 = qt * 32;

  const f16* __restrict__ kbase = kh + (size_t)b * T * HS;
  const f16* __restrict__ vbase = vhT + (size_t)b * HS * T;
  const f16* __restrict__ qp = qh + (size_t)(b * T + q0 + q31) * HS + 8 * hi;

  f16x8 qb[4];
#pragma unroll
  for (int kt = 0; kt < 4; ++kt) qb[kt] = *(const f16x8*)(qp + 16 * kt);

  f32x16 o0, o1;
#pragma unroll
  for (int i = 0; i < 16; ++i) { o0[i] = 0.f; o1[i] = 0.f; }
  float m = -1e30f, lsum = 0.f;

  const int nblk = qt + 1;
  for (int blk = w; blk < nblk; blk += 8) {
    const int kv0 = blk * 32;
    const f16* kr = kbase + (size_t)(kv0 + q31) * HS + 8 * hi;
    f16x8 ka0 = *(const f16x8*)(kr);
    f16x8 ka1 = *(const f16x8*)(kr + 16);
    f16x8 ka2 = *(const f16x8*)(kr + 32);
    f16x8 ka3 = *(const f16x8*)(kr + 48);

    f32x16 s;
#pragma unroll
    for (int i = 0; i < 16; ++i) s[i] = 0.f;
    s = __builtin_amdgcn_mfma_f32_32x32x16_f16(ka0, qb[0], s, 0, 0, 0);
    s = __builtin_amdgcn_mfma_f32_32x32x16_f16(ka1, qb[1], s, 0, 0, 0);
    s = __builtin_amdgcn_mfma_f32_32x32x16_f16(ka2, qb[2], s, 0, 0, 0);
    s = __builtin_amdgcn_mfma_f32_32x32x16_f16(ka3, qb[3], s, 0, 0, 0);

    const f16* vr = vbase + (size_t)q31 * T + kv0 + 8 * hi;
    f16x8 v00 = *(const f16x8*)(vr);
    f16x8 v01 = *(const f16x8*)(vr + 16);
    f16x8 v10 = *(const f16x8*)(vr + (size_t)32 * T);
    f16x8 v11 = *(const f16x8*)(vr + (size_t)32 * T + 16);

    if (blk == qt) {
#pragma unroll
      for (int r = 0; r < 16; ++r) {
        const int kl = (r & 3) + 8 * (r >> 2) + 4 * hi;
        if (kl > q31) s[r] = -1e30f;
      }
    }

    float pm = s[0];
#pragma unroll
    for (int r = 1; r < 16; ++r) pm = fmaxf(pm, s[r]);
    pm = fmaxf(pm, __shfl_xor(pm, 32));
    if (!__all(pm <= m + 32.f)) {
      const float mn = fmaxf(m, pm);
      const float r = EXP2((m - mn) * CEXP);
      lsum *= r;
#pragma unroll
      for (int i = 0; i < 16; ++i) { o0[i] *= r; o1[i] *= r; }
      m = mn;
    }

    float p[16];
    float ps = 0.f;
#pragma unroll
    for (int r = 0; r < 16; ++r) { p[r] = EXP2((s[r] - m) * CEXP); ps += p[r]; }
    ps += __shfl_xor(ps, 32);
    lsum += ps;

    u32 c[8], xg[8];
#pragma unroll
    for (int i = 0; i < 8; ++i) c[i] = pack2_f16(p[2 * i], p[2 * i + 1]);
#pragma unroll
    for (int i = 0; i < 8; ++i) xg[i] = (u32)__shfl_xor((int)c[i], 32);
    union { u32x4 u; f16x8 f; } f1, f2;
    f1.u = (u32x4){ hi ? xg[2] : c[0], hi ? xg[3] : c[1], hi ? c[2] : xg[0], hi ? c[3] : xg[1] };
    f2.u = (u32x4){ hi ? xg[6] : c[4], hi ? xg[7] : c[5], hi ? c[6] : xg[4], hi ? c[7] : xg[5] };

    o0 = __builtin_amdgcn_mfma_f32_32x32x16_f16(v00, f1.f, o0, 0, 0, 0);
    o0 = __builtin_amdgcn_mfma_f32_32x32x16_f16(v01, f2.f, o0, 0, 0, 0);
    o1 = __builtin_amdgcn_mfma_f32_32x32x16_f16(v10, f1.f, o1, 0, 0, 0);
    o1 = __builtin_amdgcn_mfma_f32_32x32x16_f16(v11, f2.f, o1, 0, 0, 0);
  }

  if (lane < 32) sMm[w][q31] = m;
  __syncthreads();
  float M = sMm[0][q31];
#pragma unroll
  for (int w2 = 1; w2 < 8; ++w2) M = fmaxf(M, sMm[w2][q31]);
  const float sc = EXP2((m - M) * CEXP);
  if (lane < 32) sLs[w][q31] = lsum * sc;
#pragma unroll
  for (int i = 0; i < 16; ++i) { o0[i] *= sc; o1[i] *= sc; }

  if (w >= 4) {
#pragma unroll
    for (int r = 0; r < 16; ++r) {
      const int d = (r & 3) + 8 * (r >> 2) + 4 * hi;
      sO[w - 4][d][q31] = o0[r];
      sO[w - 4][d + 32][q31] = o1[r];
    }
  }
  __syncthreads();
  if (w < 4) {
#pragma unroll
    for (int r = 0; r < 16; ++r) {
      const int d = (r & 3) + 8 * (r >> 2) + 4 * hi;
      sO[w][d][q31] += o0[r];
      sO[w][d + 32][q31] += o1[r];
    }
  }
  __syncthreads();

  const int q = tid >> 4;
  const int d0 = (tid & 15) * 4;
  float L = 0.f;
#pragma unroll
  for (int w2 = 0; w2 < 8; ++w2) L += sLs[w2][q];
  const float invL = 1.f / L;
  float4 rv;
  rv.x = (sO[0][d0 + 0][q] + sO[1][d0 + 0][q] + sO[2][d0 + 0][q] + sO[3][d0 + 0][q]) * invL;
  rv.y = (sO[0][d0 + 1][q] + sO[1][d0 + 1][q] + sO[2][d0 + 1][q] + sO[3][d0 + 1][q]) * invL;
  rv.z = (sO[0][d0 + 2][q] + sO[1][d0 + 2][q] + sO[2][d0 + 2][q] + sO[3][d0 + 2][q]) * invL;
  rv.w = (sO[0][d0 + 3][q] + sO[1][d0 + 3][q] + sO[2][d0 + 3][q] + sO[3][d0 + 3][q]) * invL;
  *(float4*)(out + (size_t)(b * T + q0 + q) * HS + d0) = rv;
}

// ---------------------------------------------------------------------------
extern "C" void kernel_launch(void* const* d_in, const int* in_sizes, int n_in,
                              void* d_out, int out_size, void* d_ws, size_t ws_size,
                              hipStream_t stream) {
  const float* q  = (const float*)d_in[0];
  const float* k  = (const float*)d_in[1];
  const float* v  = (const float*)d_in[2];
  const float* Wq = (const float*)d_in[3];
  const float* Wk = (const float*)d_in[4];
  const float* Wv = (const float*)d_in[5];
  float* out = (float*)d_out;

  f16* qh  = (f16*)d_ws;                       // [B*T][64]
  f16* kh  = qh  + (size_t)NBATCH * T * HS;    // [B*T][64]
  f16* vhT = kh  + (size_t)NBATCH * T * HS;    // [B][64][T]
  f16* WTf = vhT + (size_t)NBATCH * T * HS;    // [3][65536] fragment-packed

  wtrans_kernel<<<dim3(32, 3), 256, 0, stream>>>(Wq, Wk, Wv, WTf);
  proj_kernel<<<dim3(256), 256, 0, stream>>>(q, k, v, WTf, qh, kh, vhT);
  attn_kernel<<<dim3(T / 32 * NBATCH), 512, 0, stream>>>(qh, kh, vhT, out);
}

// Round 12
// 89.347 us; speedup vs baseline: 1.0219x; 1.0219x over previous
//
#include <hip/hip_runtime.h>
#include <hip/hip_fp16.h>

typedef _Float16 f16;
typedef __fp16 h16x2 __attribute__((ext_vector_type(2)));
typedef _Float16 f16x8 __attribute__((ext_vector_type(8)));
typedef _Float16 f16x4v __attribute__((ext_vector_type(4)));
typedef float f32x4 __attribute__((ext_vector_type(4)));
typedef float f32x16 __attribute__((ext_vector_type(16)));
typedef unsigned int u32;
typedef u32 u32x2 __attribute__((ext_vector_type(2)));
typedef u32 u32x4 __attribute__((ext_vector_type(4)));

constexpr int DM = 1024;
constexpr int HS = 64;
constexpr int NBATCH = 4;
constexpr int T = 4096;
constexpr float CEXP = 0.18033688011112042f; // 0.125 * log2(e)

#if __has_builtin(__builtin_amdgcn_exp2f)
#define EXP2(x) __builtin_amdgcn_exp2f(x)
#else
#define EXP2(x) exp2f(x)
#endif

static __device__ __forceinline__ u32 pack2_f16(float a, float b) {
  union { f16 h[2]; u32 u; } cv;
  cv.h[0] = (f16)a; cv.h[1] = (f16)b;
  return cv.u;
}

static __device__ __forceinline__ u32 pkrtz(float a, float b) {
  union { h16x2 h; u32 u; } cv;
  cv.h = __builtin_amdgcn_cvt_pkrtz(a, b);
  return cv.u;
}

static __device__ __forceinline__ void gload_lds16(const void* g, void* l) {
  __builtin_amdgcn_global_load_lds(
      (__attribute__((address_space(1))) void*)(g),
      (__attribute__((address_space(3))) void*)(l), 16, 0, 0);
}

// ---------------------------------------------------------------------------
// Prepass: W [1024][64] fp32 -> WTf fragment-packed fp16:
// WTf[which][frag = t*4+cb][lane = g*16+q15][e] = W[k = t*32+8g+e][col = cb*16+q15]
// ---------------------------------------------------------------------------
__global__ void wtrans_kernel(const float* __restrict__ Wq, const float* __restrict__ Wk,
                              const float* __restrict__ Wv, f16* __restrict__ WTf) {
  const int which = blockIdx.y;
  const float* __restrict__ W = (which == 0) ? Wq : ((which == 1) ? Wk : Wv);
  const int o8 = blockIdx.x * 256 + threadIdx.x;   // 0 .. 8191
  const int t = o8 >> 8;
  const int cb = (o8 >> 6) & 3;
  const int g = (o8 >> 4) & 3;
  const int q15 = o8 & 15;
  const int col = cb * 16 + q15;
  f16x8 v;
#pragma unroll
  for (int e = 0; e < 8; ++e) v[e] = (f16)W[(t * 32 + 8 * g + e) * 64 + col];
  *(f16x8*)(WTf + which * 65536 + o8 * 8) = v;
}

// ---------------------------------------------------------------------------
// Projections v10: CONTIGUOUS A-reads via LDS redistribution.
// Every A global-load instruction is ONE contiguous 1KB run of ONE row
// (lane l -> row r, bytes l*16) — the m13-copy access pattern — testing the
// hypothesis that the r5-r11 ~2.6TB/s wall is the row-strided request
// fragmentation. Block = 256 thr = 4 waves, 256 rows, one input. B (128KB
// WTf) LDS-resident once. A: asm loads depth-4 sets (4 rows x 1KB quarter
// per set per wave), reg->fp16 cvt, ds_write into double-buffered 8KB
// quarter-window with per-row XOR granule swizzle (conflict-free frag reads).
// Counted vmcnt(12); ALL output stores deferred to the end (stores would
// corrupt counted vmcnt waits). acc[16][4] in regs (~1 block/CU, VGPR free).
// ---------------------------------------------------------------------------
__global__ __launch_bounds__(256, 1) void proj_kernel(
    const float* __restrict__ xq, const float* __restrict__ xk, const float* __restrict__ xv,
    const f16* __restrict__ WTf, f16* __restrict__ qh, f16* __restrict__ kh,
    f16* __restrict__ vhT) {
  __shared__ __align__(16) char Bs[131072];
  __shared__ __align__(16) char Aw[2][8192];   // [buf][16 rows x 512B fp16 quarter]

  const int which = blockIdx.y;
  const float* __restrict__ x = (which == 0) ? xq : ((which == 1) ? xk : xv);
  const int tid = threadIdx.x;
  const int lane = tid & 63, w = tid >> 6;
  const int q15 = lane & 15, g = lane >> 4;
  const int rowblk = blockIdx.x * 256;

  // ---- stage B once: 128KB, 32 gloads per wave (vmcnt-counted: 32)
  const char* __restrict__ wsrc = (const char*)(WTf + (size_t)which * 65536);
#pragma unroll
  for (int j = 0; j < 32; ++j) {
    const int idx = j * 4 + w;
    gload_lds16(wsrc + idx * 1024 + lane * 16, &Bs[idx * 1024]);
  }
  __builtin_amdgcn_sched_barrier(0);

  // ---- A staging geometry: set S (0..63): row-group rg=S>>2 (16 rows),
  // k-quarter kq=S&3 (1KB of the 4KB row). Wave w stages rows rg*16+w*4+i,
  // instruction = contiguous 1KB (lane l -> +l*16).
  const size_t abase = (size_t)((const char*)x +
      ((size_t)rowblk + w * 4) * 4096 + lane * 16);
  f32x4 ld[4][4];

#define AISSUE(slot, S)                                                          \
  {                                                                              \
    const size_t ab = abase + (size_t)((S) >> 2) * 65536 + (size_t)((S) & 3) * 1024; \
    asm volatile("global_load_dwordx4 %0, %1, off" : "=v"(ld[slot][0]) : "v"(ab));          \
    asm volatile("global_load_dwordx4 %0, %1, off" : "=v"(ld[slot][1]) : "v"(ab + 4096));   \
    asm volatile("global_load_dwordx4 %0, %1, off" : "=v"(ld[slot][2]) : "v"(ab + 8192));   \
    asm volatile("global_load_dwordx4 %0, %1, off" : "=v"(ld[slot][3]) : "v"(ab + 12288));  \
  }

  // writer LDS offsets: lane l covers fp16 bytes [l*8..+8) of row (w*4+i)'s
  // quarter; stored at granule (l>>1)^(row&7)  [XOR swizzle, 16B granules]
  int wb[4];
#pragma unroll
  for (int i = 0; i < 4; ++i) {
    const int rw = w * 4 + i;
    wb[i] = rw * 512 + (((lane >> 1) ^ (rw & 7)) * 16) + (lane & 1) * 8;
  }

#define AWRITE(slot, S)                                                          \
  {                                                                              \
    char* dst = &Aw[(S) & 1][0];                                                 \
    _Pragma("unroll") for (int i = 0; i < 4; ++i) {                              \
      u32x2 pv;                                                                  \
      pv[0] = pkrtz(ld[slot][i][0], ld[slot][i][1]);                             \
      pv[1] = pkrtz(ld[slot][i][2], ld[slot][i][3]);                             \
      *(u32x2*)(dst + wb[i]) = pv;                                               \
    }                                                                            \
  }

  f32x4 acc[16];
#pragma unroll
  for (int r = 0; r < 16; ++r) acc[r] = (f32x4){0.f, 0.f, 0.f, 0.f};

  // reader: lane (q15,g), local kstep t: granule (4t+g)^(q15&7) of row q15
  const int rx = q15 & 7;

#define ACOMP(q)                                                                 \
  {                                                                              \
    const char* ab2 = &Aw[(q) & 1][0] + q15 * 512;                               \
    _Pragma("unroll") for (int t = 0; t < 8; ++t) {                              \
      const f16x8 af = *(const f16x8*)(ab2 + (((4 * t + g) ^ rx) * 16));         \
      const f16x8 bf = *(const f16x8*)(&Bs[((((q) & 3) * 8 + t) * 4 + w) * 1024 + lane * 16]); \
      acc[(q) >> 2] = __builtin_amdgcn_mfma_f32_16x16x32_f16(af, bf, acc[(q) >> 2], 0, 0, 0); \
    }                                                                            \
  }

  // ---- prologue: sets 0..3 in flight; land set 0; write; refill slot 0
  AISSUE(0, 0) AISSUE(1, 1) AISSUE(2, 2) AISSUE(3, 3)
  asm volatile("s_waitcnt vmcnt(12)" ::: "memory");   // B(32) + set0 drained
  __builtin_amdgcn_sched_barrier(0);
  AWRITE(0, 0)
  AISSUE(0, 4)
  asm volatile("s_waitcnt lgkmcnt(0)" ::: "memory");
  __builtin_amdgcn_sched_barrier(0);
  __builtin_amdgcn_s_barrier();
  __builtin_amdgcn_sched_barrier(0);

  // ---- 64 steps: write set q+1 -> buf[(q+1)&1], issue set q+5, compute q
#pragma unroll
  for (int q = 0; q < 64; ++q) {
    if (q <= 59)      asm volatile("s_waitcnt vmcnt(12)" ::: "memory");
    else if (q == 60) asm volatile("s_waitcnt vmcnt(8)" ::: "memory");
    else if (q == 61) asm volatile("s_waitcnt vmcnt(4)" ::: "memory");
    else if (q == 62) asm volatile("s_waitcnt vmcnt(0)" ::: "memory");
    __builtin_amdgcn_sched_barrier(0);
    if (q <= 62) {
      const int slot = (q + 1) & 3;
      AWRITE(slot, q + 1)
      if (q + 5 <= 63) AISSUE(slot, q + 5)
    }
    ACOMP(q)
    asm volatile("s_waitcnt lgkmcnt(0)" ::: "memory");
    __builtin_amdgcn_sched_barrier(0);
    __builtin_amdgcn_s_barrier();
    __builtin_amdgcn_sched_barrier(0);
  }
#undef AISSUE
#undef AWRITE
#undef ACOMP

  // ---- deferred stores: wave w owns cols [w*16..w*16+16)
  if (which < 2) {
    f16* __restrict__ outp = (which == 0) ? qh : kh;
#pragma unroll
    for (int rg = 0; rg < 16; ++rg) {
      const int row0 = rowblk + rg * 16;
#pragma unroll
      for (int j = 0; j < 4; ++j)
        outp[(size_t)(row0 + 4 * g + j) * HS + w * 16 + q15] = (f16)acc[rg][j];
    }
  } else {
    const int b = rowblk >> 12;
    const int col = w * 16 + q15;
#pragma unroll
    for (int rg = 0; rg < 16; ++rg) {
      const int t0 = ((rowblk + rg * 16) & (T - 1)) + 4 * g;
      f16x4v pv;
#pragma unroll
      for (int j = 0; j < 4; ++j) pv[j] = (f16)acc[rg][j];
      *(f16x4v*)(vhT + (size_t)b * HS * T + (size_t)col * T + t0) = pv;
    }
  }
}

// ---------------------------------------------------------------------------
// Causal flash attention: 32x32x16 MFMA, swapped form. (unchanged)
// ---------------------------------------------------------------------------
__global__ __launch_bounds__(512, 4) void attn_kernel(
    const f16* __restrict__ qh, const f16* __restrict__ kh,
    const f16* __restrict__ vhT, float* __restrict__ out) {
  __shared__ float sO[4][64][33];
  __shared__ float sMm[8][32];
  __shared__ float sLs[8][32];

  const int tid = threadIdx.x;
  const int lane = tid & 63, w = tid >> 6;
  const int q31 = lane & 31, hi = lane >> 5;

  const int id = blockIdx.x;
  const int b = (id & 7) >> 1;
  const int qt = 127 - 2 * (id >> 3) - (id & 1);
  const int q0 = qt * 32;

  const f16* __restrict__ kbase = kh + (size_t)b * T * HS;
  const f16* __restrict__ vbase = vhT + (size_t)b * HS * T;
  const f16* __restrict__ qp = qh + (size_t)(b * T + q0 + q31) * HS + 8 * hi;

  f16x8 qb[4];
#pragma unroll
  for (int kt = 0; kt < 4; ++kt) qb[kt] = *(const f16x8*)(qp + 16 * kt);

  f32x16 o0, o1;
#pragma unroll
  for (int i = 0; i < 16; ++i) { o0[i] = 0.f; o1[i] = 0.f; }
  float m = -1e30f, lsum = 0.f;

  const int nblk = qt + 1;
  for (int blk = w; blk < nblk; blk += 8) {
    const int kv0 = blk * 32;
    const f16* kr = kbase + (size_t)(kv0 + q31) * HS + 8 * hi;
    f16x8 ka0 = *(const f16x8*)(kr);
    f16x8 ka1 = *(const f16x8*)(kr + 16);
    f16x8 ka2 = *(const f16x8*)(kr + 32);
    f16x8 ka3 = *(const f16x8*)(kr + 48);

    f32x16 s;
#pragma unroll
    for (int i = 0; i < 16; ++i) s[i] = 0.f;
    s = __builtin_amdgcn_mfma_f32_32x32x16_f16(ka0, qb[0], s, 0, 0, 0);
    s = __builtin_amdgcn_mfma_f32_32x32x16_f16(ka1, qb[1], s, 0, 0, 0);
    s = __builtin_amdgcn_mfma_f32_32x32x16_f16(ka2, qb[2], s, 0, 0, 0);
    s = __builtin_amdgcn_mfma_f32_32x32x16_f16(ka3, qb[3], s, 0, 0, 0);

    const f16* vr = vbase + (size_t)q31 * T + kv0 + 8 * hi;
    f16x8 v00 = *(const f16x8*)(vr);
    f16x8 v01 = *(const f16x8*)(vr + 16);
    f16x8 v10 = *(const f16x8*)(vr + (size_t)32 * T);
    f16x8 v11 = *(const f16x8*)(vr + (size_t)32 * T + 16);

    if (blk == qt) {
#pragma unroll
      for (int r = 0; r < 16; ++r) {
        const int kl = (r & 3) + 8 * (r >> 2) + 4 * hi;
        if (kl > q31) s[r] = -1e30f;
      }
    }

    float pm = s[0];
#pragma unroll
    for (int r = 1; r < 16; ++r) pm = fmaxf(pm, s[r]);
    pm = fmaxf(pm, __shfl_xor(pm, 32));
    if (!__all(pm <= m + 32.f)) {
      const float mn = fmaxf(m, pm);
      const float r = EXP2((m - mn) * CEXP);
      lsum *= r;
#pragma unroll
      for (int i = 0; i < 16; ++i) { o0[i] *= r; o1[i] *= r; }
      m = mn;
    }

    float p[16];
    float ps = 0.f;
#pragma unroll
    for (int r = 0; r < 16; ++r) { p[r] = EXP2((s[r] - m) * CEXP); ps += p[r]; }
    ps += __shfl_xor(ps, 32);
    lsum += ps;

    u32 c[8], xg[8];
#pragma unroll
    for (int i = 0; i < 8; ++i) c[i] = pack2_f16(p[2 * i], p[2 * i + 1]);
#pragma unroll
    for (int i = 0; i < 8; ++i) xg[i] = (u32)__shfl_xor((int)c[i], 32);
    union { u32x4 u; f16x8 f; } f1, f2;
    f1.u = (u32x4){ hi ? xg[2] : c[0], hi ? xg[3] : c[1], hi ? c[2] : xg[0], hi ? c[3] : xg[1] };
    f2.u = (u32x4){ hi ? xg[6] : c[4], hi ? xg[7] : c[5], hi ? c[6] : xg[4], hi ? c[7] : xg[5] };

    o0 = __builtin_amdgcn_mfma_f32_32x32x16_f16(v00, f1.f, o0, 0, 0, 0);
    o0 = __builtin_amdgcn_mfma_f32_32x32x16_f16(v01, f2.f, o0, 0, 0, 0);
    o1 = __builtin_amdgcn_mfma_f32_32x32x16_f16(v10, f1.f, o1, 0, 0, 0);
    o1 = __builtin_amdgcn_mfma_f32_32x32x16_f16(v11, f2.f, o1, 0, 0, 0);
  }

  if (lane < 32) sMm[w][q31] = m;
  __syncthreads();
  float M = sMm[0][q31];
#pragma unroll
  for (int w2 = 1; w2 < 8; ++w2) M = fmaxf(M, sMm[w2][q31]);
  const float sc = EXP2((m - M) * CEXP);
  if (lane < 32) sLs[w][q31] = lsum * sc;
#pragma unroll
  for (int i = 0; i < 16; ++i) { o0[i] *= sc; o1[i] *= sc; }

  if (w >= 4) {
#pragma unroll
    for (int r = 0; r < 16; ++r) {
      const int d = (r & 3) + 8 * (r >> 2) + 4 * hi;
      sO[w - 4][d][q31] = o0[r];
      sO[w - 4][d + 32][q31] = o1[r];
    }
  }
  __syncthreads();
  if (w < 4) {
#pragma unroll
    for (int r = 0; r < 16; ++r) {
      const int d = (r & 3) + 8 * (r >> 2) + 4 * hi;
      sO[w][d][q31] += o0[r];
      sO[w][d + 32][q31] += o1[r];
    }
  }
  __syncthreads();

  const int q = tid >> 4;
  const int d0 = (tid & 15) * 4;
  float L = 0.f;
#pragma unroll
  for (int w2 = 0; w2 < 8; ++w2) L += sLs[w2][q];
  const float invL = 1.f / L;
  float4 rv;
  rv.x = (sO[0][d0 + 0][q] + sO[1][d0 + 0][q] + sO[2][d0 + 0][q] + sO[3][d0 + 0][q]) * invL;
  rv.y = (sO[0][d0 + 1][q] + sO[1][d0 + 1][q] + sO[2][d0 + 1][q] + sO[3][d0 + 1][q]) * invL;
  rv.z = (sO[0][d0 + 2][q] + sO[1][d0 + 2][q] + sO[2][d0 + 2][q] + sO[3][d0 + 2][q]) * invL;
  rv.w = (sO[0][d0 + 3][q] + sO[1][d0 + 3][q] + sO[2][d0 + 3][q] + sO[3][d0 + 3][q]) * invL;
  *(float4*)(out + (size_t)(b * T + q0 + q) * HS + d0) = rv;
}

// ---------------------------------------------------------------------------
extern "C" void kernel_launch(void* const* d_in, const int* in_sizes, int n_in,
                              void* d_out, int out_size, void* d_ws, size_t ws_size,
                              hipStream_t stream) {
  const float* q  = (const float*)d_in[0];
  const float* k  = (const float*)d_in[1];
  const float* v  = (const float*)d_in[2];
  const float* Wq = (const float*)d_in[3];
  const float* Wk = (const float*)d_in[4];
  const float* Wv = (const float*)d_in[5];
  float* out = (float*)d_out;

  f16* qh  = (f16*)d_ws;                       // [B*T][64]
  f16* kh  = qh  + (size_t)NBATCH * T * HS;    // [B*T][64]
  f16* vhT = kh  + (size_t)NBATCH * T * HS;    // [B][64][T]
  f16* WTf = vhT + (size_t)NBATCH * T * HS;    // [3][65536] fragment-packed

  wtrans_kernel<<<dim3(32, 3), 256, 0, stream>>>(Wq, Wk, Wv, WTf);
  proj_kernel<<<dim3(64, 3), 256, 0, stream>>>(q, k, v, WTf, qh, kh, vhT);
  attn_kernel<<<dim3(T / 32 * NBATCH), 512, 0, stream>>>(qh, kh, vhT, out);
}